// Round 9
// baseline (417.498 us; speedup 1.0000x reference)
//
#include <hip/hip_runtime.h>
#include <hip/hip_bf16.h>

// Problem constants
#define NTOK 2048
#define DIM 1024
#define NH 16
#define KVH 8
#define GQ 2
#define HD 64
#define WS 64
#define CBS 32
#define STRIDE 16
#define SEL_BLK 32
#define NSEL 4
#define NMEM 1
#define NCB 128          // N/STRIDE
#define NFB 64           // N/SEL_BLK
#define HIDN 2048        // CBS*D
#define SCALE 0.125f
#define NEGF (-3.4028234663852886e38f)
#define NEG10F (-3.4028234663852886e37f)

typedef __attribute__((ext_vector_type(8))) short bf16x8;
typedef __attribute__((ext_vector_type(4))) float f32x4;
typedef _Float16 f16x2 __attribute__((ext_vector_type(2)));

__device__ __forceinline__ float bflo(unsigned u) { return __uint_as_float(u << 16); }
__device__ __forceinline__ float bfhi(unsigned u) { return __uint_as_float(u & 0xffff0000u); }

// f16 packed fragment: 16 halfs = 2 uint4 = 8 half2
union HU { uint4 v[2]; f16x2 h[8]; };

// dot of 16 f16 elems (k) against two queries via v_dot2_f32_f16:
// 4 independent f32 accumulator chains (depth 4) -> keeps ILP (round-5 lesson:
// packed-f16 FMA with 2 chains of 8 was latency-bound).
__device__ __forceinline__ void dot16d(const HU& k, const HU& qa, const HU& qb,
                                       float& s0, float& s1) {
    float a0 = 0.f, a1 = 0.f, b0 = 0.f, b1 = 0.f;
#pragma unroll
    for (int j = 0; j < 8; j += 2) {
        a0 = __builtin_amdgcn_fdot2(k.h[j], qa.h[j], a0, false);
        a1 = __builtin_amdgcn_fdot2(k.h[j + 1], qa.h[j + 1], a1, false);
        b0 = __builtin_amdgcn_fdot2(k.h[j], qb.h[j], b0, false);
        b1 = __builtin_amdgcn_fdot2(k.h[j + 1], qb.h[j + 1], b1, false);
    }
    s0 += a0 + a1;
    s1 += b0 + b1;
}

// async 16B global -> LDS (LDS dest must be wave-uniform base + lane*16)
__device__ __forceinline__ void gload_lds16(const void* g, void* l) {
    __builtin_amdgcn_global_load_lds((const __attribute__((address_space(1))) unsigned*)g,
                                     (__attribute__((address_space(3))) unsigned*)l, 16, 0, 0);
}

// ---------------- RMSNorm body (f32 x output removed: dead) ----------------
__device__ __forceinline__ void rms_body(const float* __restrict__ inp,
                                         const float* __restrict__ g,
                                         __hip_bfloat16* __restrict__ xb, int n) {
    const float* row = inp + (size_t)n * DIM;
    float ss = 0.f;
    for (int c = threadIdx.x; c < DIM; c += 256) { float v = row[c]; ss += v * v; }
    __shared__ float red[4];
    for (int o = 32; o; o >>= 1) ss += __shfl_down(ss, o, 64);
    if ((threadIdx.x & 63) == 0) red[threadIdx.x >> 6] = ss;
    __syncthreads();
    if (threadIdx.x == 0) red[0] = red[0] + red[1] + red[2] + red[3];
    __syncthreads();
    float rs = 1.0f / sqrtf(red[0] / (float)DIM + 1.1920928955078125e-07f);
    __hip_bfloat16* xbr = xb + (size_t)n * DIM;
    for (int c = threadIdx.x; c < DIM; c += 256) {
        float v = row[c] * rs * g[c];
        xbr[c] = __float2bfloat16(v);
    }
}

// ---------------- transpose body ----------------
__device__ __forceinline__ void transpose_body(const float* __restrict__ B,
                                               __hip_bfloat16* __restrict__ Bt,
                                               int K, int N, int bx, int by) {
    __shared__ float tile[32][33];
    int n0 = bx * 32, k0 = by * 32;
    int x = threadIdx.x & 31, y = threadIdx.x >> 5;
    for (int i = 0; i < 4; i++) {
        int k = k0 + y + 8 * i, n = n0 + x;
        tile[y + 8 * i][x] = (k < K && n < N) ? B[(size_t)k * N + n] : 0.f;
    }
    __syncthreads();
    for (int i = 0; i < 4; i++) {
        int n = n0 + y + 8 * i, k = k0 + x;
        if (n < N && k < K) Bt[(size_t)n * K + k] = __float2bfloat16(tile[x][y + 8 * i]);
    }
}

// ---------------- pre: rmsnorm + all transposes + bias inits ----------------
__global__ __launch_bounds__(256) void pre_kernel(
    const float* inp, const float* norm_g, __hip_bfloat16* xb,
    const float* Wqkv, __hip_bfloat16* Wqkvt,
    const float* kW1, __hip_bfloat16* kW1t,
    const float* vW1, __hip_bfloat16* vW1t,
    const float* Wout, __hip_bfloat16* Woutt,
    const float* combW, __hip_bfloat16* combWt,
    const float* kW2, __hip_bfloat16* kW2t,
    const float* vW2, __hip_bfloat16* vW2t,
    const float* combB, float* gatesb,
    const float* kb2, float* ckraw,
    const float* vb2, float* cvraw) {
    int b = blockIdx.x;
    if (b < 2048) { rms_body(inp, norm_g, xb, b); return; }
    b -= 2048;
    if (b < 2048) { transpose_body(Wqkv, Wqkvt, 1024, 2048, b % 64, b / 64); return; }
    b -= 2048;
    if (b < 4096) { transpose_body(kW1, kW1t, 2048, 2048, b % 64, b / 64); return; }
    b -= 4096;
    if (b < 4096) { transpose_body(vW1, vW1t, 2048, 2048, b % 64, b / 64); return; }
    b -= 4096;
    if (b < 1024) { transpose_body(Wout, Woutt, 1024, 1024, b % 32, b / 32); return; }
    b -= 1024;
    if (b < 64) { transpose_body(combW, combWt, 1024, 48, b % 2, b / 2); return; }
    b -= 64;
    if (b < 128) { transpose_body(kW2, kW2t, 2048, 64, b % 2, b / 2); return; }
    b -= 128;
    if (b < 128) { transpose_body(vW2, vW2t, 2048, 64, b % 2, b / 2); return; }
    b -= 128;
    if (b < 384) {  // gates bias init: 2048*48
        int idx = b * 256 + threadIdx.x;
        if (idx < 2048 * 48) gatesb[idx] = combB[idx % 48];
        return;
    }
    b -= 384;
    {   // ck/cv bias init: 2*1024*64
        int idx = b * 256 + threadIdx.x;
        int tot = 1024 * 64;
        if (idx < tot) ckraw[idx] = kb2[idx % 64];
        else if (idx < 2 * tot) { idx -= tot; cvraw[idx] = vb2[idx % 64]; }
        return;
    }
}
#define PRE_BLOCKS (2048 + 2048 + 4096 + 4096 + 1024 + 64 + 128 + 128 + 384 + 512)

// ---------------- 128x64-tile bf16 MFMA GEMM body (2+ blocks/CU occupancy) --------
template <int ACT, int OUTBF16>
__device__ __forceinline__ void gemm64_body(const __hip_bfloat16* __restrict__ A,
                                            const __hip_bfloat16* __restrict__ Bt,
                                            const float* __restrict__ bias,
                                            void* __restrict__ Cp,
                                            int M, int N, int K, int bx, int by) {
    __shared__ __align__(16) short As2[128 * 32];
    __shared__ __align__(16) short Bs2[64 * 32];
    int tid = threadIdx.x;
    int lane = tid & 63, wave = tid >> 6;
    int m0 = by * 128, n0 = bx * 64;
    int wm = wave * 32;
    f32x4 acc[2][4];
    for (int r = 0; r < 2; r++)
        for (int c = 0; c < 4; c++) acc[r][c] = (f32x4){0.f, 0.f, 0.f, 0.f};

    int ra = tid >> 2, kc = (tid & 3) * 8;
    for (int k0 = 0; k0 < K; k0 += 32) {
        __syncthreads();
        gload_lds16(A + (size_t)(m0 + ra) * K + k0 + kc, &As2[ra * 32 + kc]);
        gload_lds16(A + (size_t)(m0 + ra + 64) * K + k0 + kc, &As2[(ra + 64) * 32 + kc]);
        gload_lds16(Bt + (size_t)(n0 + ra) * K + k0 + kc, &Bs2[ra * 32 + kc]);
        __syncthreads();
        bf16x8 af[2], bfr[4];
#pragma unroll
        for (int r = 0; r < 2; r++)
            af[r] = *(const bf16x8*)&As2[(wm + r * 16 + (lane & 15)) * 32 + (lane >> 4) * 8];
#pragma unroll
        for (int c = 0; c < 4; c++)
            bfr[c] = *(const bf16x8*)&Bs2[(c * 16 + (lane & 15)) * 32 + (lane >> 4) * 8];
#pragma unroll
        for (int r = 0; r < 2; r++)
#pragma unroll
            for (int c = 0; c < 4; c++)
                acc[r][c] = __builtin_amdgcn_mfma_f32_16x16x32_bf16(af[r], bfr[c], acc[r][c], 0, 0, 0);
    }
    for (int r = 0; r < 2; r++) {
        int grow = m0 + wm + r * 16 + (lane >> 4) * 4;
        for (int c = 0; c < 4; c++) {
            int gcol = n0 + c * 16 + (lane & 15);
            float bv = bias ? bias[gcol] : 0.f;
#pragma unroll
            for (int v = 0; v < 4; v++) {
                float val = acc[r][c][v] + bv;
                if (ACT == 1) val = fmaxf(val, 0.f);
                if (OUTBF16)
                    ((__hip_bfloat16*)Cp)[(size_t)(grow + v) * N + gcol] = __float2bfloat16(val);
                else
                    ((float*)Cp)[(size_t)(grow + v) * N + gcol] = val;
            }
        }
    }
}

template <int ACT, int OUTBF16>
__global__ __launch_bounds__(256) void gemm64(const __hip_bfloat16* __restrict__ A,
                                              const __hip_bfloat16* __restrict__ Bt,
                                              const float* __restrict__ bias,
                                              void* __restrict__ Cp,
                                              int M, int N, int K) {
    gemm64_body<ACT, OUTBF16>(A, Bt, bias, Cp, M, N, K, blockIdx.x, blockIdx.y);
}

__global__ __launch_bounds__(256) void gemm64_pair(const __hip_bfloat16* A0,
                                                   const __hip_bfloat16* A1,
                                                   const __hip_bfloat16* Bt0,
                                                   const __hip_bfloat16* Bt1,
                                                   const float* bias0, const float* bias1,
                                                   __hip_bfloat16* C0, __hip_bfloat16* C1,
                                                   int M, int N, int K) {
    if (blockIdx.z == 0)
        gemm64_body<1, 1>(A0, Bt0, bias0, C0, M, N, K, blockIdx.x, blockIdx.y);
    else
        gemm64_body<1, 1>(A1, Bt1, bias1, C1, M, N, K, blockIdx.x, blockIdx.y);
}

// ---------------- Split-K skinny MFMA GEMM body: C += A @ Bt^T (atomicAdd) ----------
__device__ __forceinline__ void skgemm_body(const __hip_bfloat16* __restrict__ A,
                                            const __hip_bfloat16* __restrict__ Bt,
                                            float* __restrict__ C,
                                            int M, int Nout, int K, int by, int bz, int nz) {
    __shared__ __align__(16) short As2[128 * 32];
    __shared__ __align__(16) short Bs2[64 * 32];
    int tid = threadIdx.x;
    int lane = tid & 63, wave = tid >> 6;
    int m0 = by * 128;
    int wm = wave * 32;
    int kchunk = K / nz;
    int kbase = bz * kchunk;
    f32x4 acc[2][4];
    for (int r = 0; r < 2; r++)
        for (int c = 0; c < 4; c++) acc[r][c] = (f32x4){0.f, 0.f, 0.f, 0.f};

    int ra = tid >> 2, kc = (tid & 3) * 8;
    int rb = ra < Nout ? ra : Nout - 1;
    for (int k0 = kbase; k0 < kbase + kchunk; k0 += 32) {
        __syncthreads();
        gload_lds16(A + (size_t)(m0 + ra) * K + k0 + kc, &As2[ra * 32 + kc]);
        gload_lds16(A + (size_t)(m0 + ra + 64) * K + k0 + kc, &As2[(ra + 64) * 32 + kc]);
        gload_lds16(Bt + (size_t)rb * K + k0 + kc, &Bs2[ra * 32 + kc]);
        __syncthreads();
        bf16x8 af[2], bfr[4];
#pragma unroll
        for (int r = 0; r < 2; r++)
            af[r] = *(const bf16x8*)&As2[(wm + r * 16 + (lane & 15)) * 32 + (lane >> 4) * 8];
#pragma unroll
        for (int c = 0; c < 4; c++)
            bfr[c] = *(const bf16x8*)&Bs2[(c * 16 + (lane & 15)) * 32 + (lane >> 4) * 8];
#pragma unroll
        for (int r = 0; r < 2; r++)
#pragma unroll
            for (int c = 0; c < 4; c++)
                acc[r][c] = __builtin_amdgcn_mfma_f32_16x16x32_bf16(af[r], bfr[c], acc[r][c], 0, 0, 0);
    }
    for (int r = 0; r < 2; r++) {
        int grow = m0 + wm + r * 16 + (lane >> 4) * 4;
        for (int c = 0; c < 4; c++) {
            int gcol = c * 16 + (lane & 15);
            if (gcol >= Nout) continue;
#pragma unroll
            for (int v = 0; v < 4; v++)
                atomicAdd(&C[(size_t)(grow + v) * Nout + gcol], acc[r][c][v]);
        }
    }
}

// ---------------- qkv GEMM + gates split-K in one launch ----------------
__global__ __launch_bounds__(256) void qkv_gates_kernel(const __hip_bfloat16* xb,
                                                        const __hip_bfloat16* Wqkvt,
                                                        float* qkv,
                                                        const __hip_bfloat16* combWt,
                                                        float* gatesb) {
    int b = blockIdx.x;
    if (b < 512) {
        gemm64_body<0, 0>(xb, Wqkvt, nullptr, qkv, 2048, 2048, 1024, b & 31, b >> 5);
    } else {
        int s = b - 512;  // 64 blocks: by = s&15, bz = s>>4 (nz=4)
        skgemm_body(xb, combWt, gatesb, 2048, 48, 1024, s & 15, s >> 4, 4);
    }
}

__global__ __launch_bounds__(256) void skgemm_pair(const __hip_bfloat16* A0,
                                                   const __hip_bfloat16* A1,
                                                   const __hip_bfloat16* Bt0,
                                                   const __hip_bfloat16* Bt1,
                                                   float* C0, float* C1,
                                                   int M, int Nout, int K) {
    if (blockIdx.x == 0)
        skgemm_body(A0, Bt0, C0, M, Nout, K, blockIdx.y, blockIdx.z, gridDim.z);
    else
        skgemm_body(A1, Bt1, C1, M, Nout, K, blockIdx.y, blockIdx.z, gridDim.z);
}

// ---------------- buildwin + rope fused (Q and K written as f16) ----------------
__global__ __launch_bounds__(256) void winrope_kernel(const float* __restrict__ qkv,
                                                      const float* __restrict__ k_pos,
                                                      const float* __restrict__ v_pos,
                                                      __hip_bfloat16* __restrict__ kwflat,
                                                      __hip_bfloat16* __restrict__ vwflat,
                                                      _Float16* __restrict__ rqh,
                                                      _Float16* __restrict__ rkh,
                                                      __hip_bfloat16* __restrict__ vt) {
    int b = blockIdx.x;
    int t = threadIdx.x;
    if (b < 4096) {
        size_t total = (size_t)(KVH * NCB) * HIDN;
        for (size_t e = (size_t)b * 256 + t; e < total; e += (size_t)4096 * 256) {
            int r = (int)(e >> 11);
            int c = (int)(e & 2047);
            int j = c >> 6, d = c & 63;
            int h = r >> 7, i = r & 127;
            int p = i * STRIDE + j - (CBS - STRIDE);
            float kb = k_pos[((size_t)h * CBS + j) * HD + d];
            float vb = v_pos[((size_t)h * CBS + j) * HD + d];
            float kv = 0.f, vv = 0.f;
            if (p >= 0) {
                kv = qkv[(size_t)p * 2048 + 1024 + h * HD + d];
                vv = qkv[(size_t)p * 2048 + 1536 + h * HD + d];
            }
            kwflat[e] = __float2bfloat16(kv + kb);
            vwflat[e] = __float2bfloat16(vv + vb);
        }
        return;
    }
    int n = b - 4096;
    for (int idx = t; idx < NH * 32; idx += 256) {
        int h = idx >> 5, f = idx & 31;
        float inv = exp2f((float)f * -0.41524101186092f);
        float ang = (float)n * inv;
        float cc = cosf(ang), ssn = sinf(ang);
        float a = qkv[(size_t)n * 2048 + h * HD + 2 * f];
        float bq = qkv[(size_t)n * 2048 + h * HD + 2 * f + 1];
        _Float16* o = rqh + ((size_t)h * NTOK + n) * HD + 2 * f;
        o[0] = (_Float16)(a * cc - bq * ssn);
        o[1] = (_Float16)(bq * cc + a * ssn);
    }
    for (int idx = t; idx < KVH * 32; idx += 256) {
        int h = idx >> 5, f = idx & 31;
        float inv = exp2f((float)f * -0.41524101186092f);
        float ang = (float)n * inv;
        float cc = cosf(ang), ssn = sinf(ang);
        float a = qkv[(size_t)n * 2048 + 1024 + h * HD + 2 * f];
        float bq = qkv[(size_t)n * 2048 + 1024 + h * HD + 2 * f + 1];
        _Float16* o = rkh + ((size_t)h * NTOK + n) * HD + 2 * f;
        o[0] = (_Float16)(a * cc - bq * ssn);
        o[1] = (_Float16)(bq * cc + a * ssn);
    }
    for (int idx = t; idx < KVH * HD; idx += 256) {
        int h = idx >> 6, d = idx & 63;
        vt[((size_t)h * NTOK + n) * HD + d] =
            __float2bfloat16(qkv[(size_t)n * 2048 + 1536 + h * HD + d]);
    }
}

// ---------------- Compressed attention v3: no ck/cv LDS staging ------------------
// ckraw/cvraw (2 MB total) are L2/L1-resident: read DIRECT from global (identical
// f32 numerics -> top-k selection bit-compatible). scratch eliminated by reusing
// the dead qs buffer for the importance matrix. LDS 60.4 KB -> 51.7 KB -> 3
// blocks/CU (+50% occupancy); barriers 16 -> 4. PV remapped so each thread owns a
// contiguous dim-octet -> float4 loads/stores (8x fewer PV memory instructions).
__global__ __launch_bounds__(256) void cattn3_kernel(const float* __restrict__ qkv,
                                                     const float* __restrict__ ckraw,
                                                     const float* __restrict__ cvraw,
                                                     const float* __restrict__ memkv,
                                                     float* __restrict__ cout,
                                                     int* __restrict__ selidx,
                                                     int* __restrict__ selmask) {
    int h = blockIdx.x >> 6;
    int i0 = (blockIdx.x & 63) * 32;
    int t = threadIdx.x;
    __shared__ float qs[64][68];       // Q rows (f32); reused as importance scratch
    __shared__ float sc[64][132];      // scores -> probabilities
    __shared__ float memk[64], memv[64];

    for (int idx = t; idx < 4096; idx += 256) {
        int row = idx >> 6, d = idx & 63;
        int g = row >> 5, qi = row & 31;
        qs[row][d] = qkv[(size_t)(i0 + qi) * 2048 + (h * 2 + g) * 64 + d];
    }
    if (t < 64) { memk[t] = memkv[h * 64 + t]; memv[t] = memkv[(8 + h) * 64 + t]; }
    __syncthreads();
    if (t < 64) {
        float s = 0.f;
        for (int d = 0; d < 64; d++) s += qs[t][d] * memk[d];
        sc[t][0] = s * SCALE;
    }
    int rg = t >> 3, kg = t & 7;
    const float* ckh = ckraw + (size_t)h * 128 * 64;
#pragma unroll 1
    for (int c = 0; c < 4; c++) {
        float a0[4] = {}, a1[4] = {};
        for (int d = 0; d < 64; d += 4) {
            float4 q0 = *(const float4*)&qs[rg * 2][d];
            float4 q1 = *(const float4*)&qs[rg * 2 + 1][d];
#pragma unroll
            for (int kk = 0; kk < 4; kk++) {
                float4 kv = *(const float4*)(ckh + (size_t)(c * 32 + kg + kk * 8) * 64 + d);
                a0[kk] += q0.x * kv.x + q0.y * kv.y + q0.z * kv.z + q0.w * kv.w;
                a1[kk] += q1.x * kv.x + q1.y * kv.y + q1.z * kv.z + q1.w * kv.w;
            }
        }
#pragma unroll
        for (int kk = 0; kk < 4; kk++) {
            sc[rg * 2][1 + c * 32 + kg + kk * 8] = a0[kk] * SCALE;
            sc[rg * 2 + 1][1 + c * 32 + kg + kk * 8] = a1[kk] * SCALE;
        }
    }
    __syncthreads();
    float* impf = &qs[0][0];   // 32x66 importance matrix (qs is dead after QK)
    for (int idx = t; idx < 2048; idx += 256) {
        int qi = idx >> 6, fb = idx & 63;
        float v = 0.25f * (sc[qi][1 + 2 * fb] + sc[qi][2 + 2 * fb] +
                           sc[32 + qi][1 + 2 * fb] + sc[32 + qi][2 + 2 * fb]);
        if (fb == ((i0 + qi) >> 5)) v = NEGF;
        impf[qi * 66 + fb] = v;
    }
    __syncthreads();
    if (t < 32) {
        float* row = &impf[t * 66];
        float m = -1000.f;
        for (int j = 0; j < 64; j++) m = fmaxf(m, row[j]);
        float den = __expf(-1000.f - m);
        for (int j = 0; j < 64; j++) den += __expf(row[j] - m);
        float invd = 1.f / den;
        unsigned long long taken = 0ull;
        int mk = 0;
        size_t base = ((size_t)h * NTOK + i0 + t) * 5;
        for (int p = 0; p < NSEL; p++) {
            float bv = NEGF;
            int bi = 0;
            for (int j = 0; j < 64; j++) {
                if (!((taken >> j) & 1ull) && row[j] > bv) { bv = row[j]; bi = j; }
            }
            taken |= 1ull << bi;
            selidx[base + p] = bi;
            if (__expf(bv - m) * invd > 1e-10f) mk |= 1 << p;
        }
        selidx[base + 4] = (i0 + t) >> 5;
        selmask[h * NTOK + i0 + t] = mk;
    } else if (t >= 64 && t < 128) {
        int r = t - 64;
        float m = NEGF;
        for (int j = 0; j < 129; j++) m = fmaxf(m, sc[r][j]);
        float den = 0.f;
        for (int j = 0; j < 129; j++) { float e = __expf(sc[r][j] - m); sc[r][j] = e; den += e; }
        float inv = 1.f / den;
        for (int j = 0; j < 129; j++) sc[r][j] *= inv;
    }
    __syncthreads();
    // PV: thread owns dims [dg*8, dg*8+8); V read direct from global as float4
    int dg = t & 7;
    const float* cvh = cvraw + (size_t)h * 128 * 64;
    float o0[8], o1[8];
    {
        float p0 = sc[rg * 2][0], p1 = sc[rg * 2 + 1][0];
        float4 va = *(const float4*)&memv[dg * 8];
        float4 vb = *(const float4*)&memv[dg * 8 + 4];
        o0[0] = p0 * va.x; o0[1] = p0 * va.y; o0[2] = p0 * va.z; o0[3] = p0 * va.w;
        o0[4] = p0 * vb.x; o0[5] = p0 * vb.y; o0[6] = p0 * vb.z; o0[7] = p0 * vb.w;
        o1[0] = p1 * va.x; o1[1] = p1 * va.y; o1[2] = p1 * va.z; o1[3] = p1 * va.w;
        o1[4] = p1 * vb.x; o1[5] = p1 * vb.y; o1[6] = p1 * vb.z; o1[7] = p1 * vb.w;
    }
#pragma unroll 1
    for (int c = 0; c < 4; c++) {
        for (int jj = 0; jj < 32; jj++) {
            float p0 = sc[rg * 2][1 + c * 32 + jj];
            float p1 = sc[rg * 2 + 1][1 + c * 32 + jj];
            const float* vrow = cvh + (size_t)(c * 32 + jj) * 64 + dg * 8;
            float4 va = *(const float4*)(vrow);
            float4 vb = *(const float4*)(vrow + 4);
            o0[0] = fmaf(p0, va.x, o0[0]); o0[1] = fmaf(p0, va.y, o0[1]);
            o0[2] = fmaf(p0, va.z, o0[2]); o0[3] = fmaf(p0, va.w, o0[3]);
            o0[4] = fmaf(p0, vb.x, o0[4]); o0[5] = fmaf(p0, vb.y, o0[5]);
            o0[6] = fmaf(p0, vb.z, o0[6]); o0[7] = fmaf(p0, vb.w, o0[7]);
            o1[0] = fmaf(p1, va.x, o1[0]); o1[1] = fmaf(p1, va.y, o1[1]);
            o1[2] = fmaf(p1, va.z, o1[2]); o1[3] = fmaf(p1, va.w, o1[3]);
            o1[4] = fmaf(p1, vb.x, o1[4]); o1[5] = fmaf(p1, vb.y, o1[5]);
            o1[6] = fmaf(p1, vb.z, o1[6]); o1[7] = fmaf(p1, vb.w, o1[7]);
        }
    }
    {
        int row = rg * 2;
        int g = row >> 5, qi = row & 31;
        int g2 = (row + 1) >> 5, qi2 = (row + 1) & 31;
        float* c0p = cout + (((size_t)(h * 2 + g)) * NTOK + i0 + qi) * 64 + dg * 8;
        float* c1p = cout + (((size_t)(h * 2 + g2)) * NTOK + i0 + qi2) * 64 + dg * 8;
        *(float4*)(c0p) = (float4){o0[0], o0[1], o0[2], o0[3]};
        *(float4*)(c0p + 4) = (float4){o0[4], o0[5], o0[6], o0[7]};
        *(float4*)(c1p) = (float4){o1[0], o1[1], o1[2], o1[3]};
        *(float4*)(c1p + 4) = (float4){o1[4], o1[5], o1[6], o1[7]};
    }
}

// ---------------- Fused attention v7: fdot2 QK ------------------------------------
// Structure = v6 (K-only LDS sliding, V direct, h = blk&7 XCD swizzle). QK uses
// v_dot2_f32_f16 (__builtin_amdgcn_fdot2): 2 f16 MACs/inst, f32 accumulation,
// 4 independent accumulator chains of depth 4 (preserves ILP; round-5's hfma2
// failure was 2 chains of 8 in f16). PV unchanged (bf16 V, f32 FMA).
#define SLIDE_BLKS 1024
#define SROWS 79          // 16 queries + 63 history rows
#define SPAD 72           // shorts per K row (144 B, 16B-aligned, bank-rotated)
#define SLIDE_LDS (SROWS * SPAD * 2 + 4 * 128 * 4)   // 13424 B
__global__ __launch_bounds__(256) void attn_fused7_kernel(const _Float16* __restrict__ rqh,
                                                          const _Float16* __restrict__ rkh,
                                                          const __hip_bfloat16* __restrict__ vt,
                                                          const int* __restrict__ selidx,
                                                          const int* __restrict__ selmask,
                                                          float* __restrict__ fout,
                                                          float* __restrict__ sout) {
    int tid = threadIdx.x;
    int ws = tid >> 6, lane = tid & 63;
    __shared__ __align__(16) char smem[SLIDE_LDS];

    int kq = lane >> 2, c = lane & 3;
    int kv8 = lane >> 3, c8 = lane & 7;

    if (blockIdx.x < SLIDE_BLKS) {
        // ---------- tiled sliding-window: h = blk&7, 16-query tile ----------
        int h = blockIdx.x & 7;
        int q0 = (int)(blockIdx.x >> 3) * 16;
        short* ks = (short*)smem;
        float* ps = (float*)(smem + SROWS * SPAD * 2);
        int basek = q0 - 63;
        for (int idx = tid; idx < SROWS * 8; idx += 256) {
            int row = idx >> 3, ch = (idx & 7) * 8;
            int kpos = basek + row;
            uint4 kv = (uint4){0u, 0u, 0u, 0u};
            if (kpos >= 0)
                kv = *(const uint4*)(rkh + ((size_t)h * NTOK + kpos) * 64 + ch);
            *(uint4*)&ks[row * SPAD + ch] = kv;
        }
        __syncthreads();
        float* p0 = ps + ws * 128;
        float* p1 = p0 + 64;
#pragma unroll 1
        for (int tq = 0; tq < 4; tq++) {
            int ibase = ws * 4 + tq;
            int i = q0 + ibase;
            const _Float16* q0p = rqh + ((size_t)(h * 2 + 0) * NTOK + i) * 64 + c * 16;
            const _Float16* q1p = rqh + ((size_t)(h * 2 + 1) * NTOK + i) * 64 + c * 16;
            HU qa, qb;
            qa.v[0] = *(const uint4*)(q0p); qa.v[1] = *(const uint4*)(q0p + 8);
            qb.v[0] = *(const uint4*)(q1p); qb.v[1] = *(const uint4*)(q1p + 8);
#pragma unroll
            for (int kt = 0; kt < 4; kt++) {
                int key = kt * 16 + kq;
                const short* kr = &ks[(ibase + key) * SPAD + c * 16];
                HU kk_;
                kk_.v[0] = *(const uint4*)(kr);
                kk_.v[1] = *(const uint4*)(kr + 8);
                float s0 = 0.f, s1 = 0.f;
                dot16d(kk_, qa, qb, s0, s1);
                s0 += __shfl_xor(s0, 1); s0 += __shfl_xor(s0, 2);
                s1 += __shfl_xor(s1, 1); s1 += __shfl_xor(s1, 2);
                int kpos = i - 63 + key;
                if (c == 0) {
                    p0[key] = (kpos >= 0) ? s0 * SCALE : NEG10F;
                    p1[key] = (kpos >= 0) ? s1 * SCALE : NEG10F;
                }
            }
            // wave-local softmax over 64 (same-wave LDS ordering is program-order)
            {
                float a0 = p0[lane], a1 = p1[lane];
                float m0 = a0, m1 = a1;
#pragma unroll
                for (int o = 1; o < 64; o <<= 1) {
                    m0 = fmaxf(m0, __shfl_xor(m0, o));
                    m1 = fmaxf(m1, __shfl_xor(m1, o));
                }
                float e0 = __expf(a0 - m0), e1 = __expf(a1 - m1);
                float d0 = e0, d1 = e1;
#pragma unroll
                for (int o = 1; o < 64; o <<= 1) {
                    d0 += __shfl_xor(d0, o);
                    d1 += __shfl_xor(d1, o);
                }
                p0[lane] = e0 / d0;
                p1[lane] = e1 / d1;
            }
            // sliding PV: V direct from global (L2-resident; masked keys have p==0,
            // so clamped row index is safe)
            float o0[8] = {}, o1[8] = {};
#pragma unroll
            for (int pass = 0; pass < 8; pass++) {
                int j = pass * 8 + kv8;
                int kpos = i - 63 + j;
                int kcl = kpos >= 0 ? kpos : 0;
                uint4 v = *(const uint4*)(vt + ((size_t)h * NTOK + kcl) * 64 + c8 * 8);
                float pa = p0[j], pb = p1[j];
                float e0 = bflo(v.x), e1 = bfhi(v.x), e2 = bflo(v.y), e3 = bfhi(v.y);
                float e4 = bflo(v.z), e5 = bfhi(v.z), e6 = bflo(v.w), e7 = bfhi(v.w);
                o0[0] = fmaf(pa, e0, o0[0]); o0[1] = fmaf(pa, e1, o0[1]);
                o0[2] = fmaf(pa, e2, o0[2]); o0[3] = fmaf(pa, e3, o0[3]);
                o0[4] = fmaf(pa, e4, o0[4]); o0[5] = fmaf(pa, e5, o0[5]);
                o0[6] = fmaf(pa, e6, o0[6]); o0[7] = fmaf(pa, e7, o0[7]);
                o1[0] = fmaf(pb, e0, o1[0]); o1[1] = fmaf(pb, e1, o1[1]);
                o1[2] = fmaf(pb, e2, o1[2]); o1[3] = fmaf(pb, e3, o1[3]);
                o1[4] = fmaf(pb, e4, o1[4]); o1[5] = fmaf(pb, e5, o1[5]);
                o1[6] = fmaf(pb, e6, o1[6]); o1[7] = fmaf(pb, e7, o1[7]);
            }
#pragma unroll
            for (int o = 8; o <= 32; o <<= 1)
#pragma unroll
                for (int d = 0; d < 8; d++) {
                    o0[d] += __shfl_xor(o0[d], o);
                    o1[d] += __shfl_xor(o1[d], o);
                }
            if (kv8 == 0) {
                float* s0p = sout + ((size_t)(h * 2 + 0) * NTOK + i) * 64 + c8 * 8;
                float* s1p = sout + ((size_t)(h * 2 + 1) * NTOK + i) * 64 + c8 * 8;
                *(float4*)(s0p) = (float4){o0[0], o0[1], o0[2], o0[3]};
                *(float4*)(s0p + 4) = (float4){o0[4], o0[5], o0[6], o0[7]};
                *(float4*)(s1p) = (float4){o1[0], o1[1], o1[2], o1[3]};
                *(float4*)(s1p + 4) = (float4){o1[4], o1[5], o1[6], o1[7]};
            }
        }
    } else {
        // ---------- fine attention (wave per query), h = blk&7 ----------
        int bb = blockIdx.x - SLIDE_BLKS;
        int h = bb & 7;
        int i = (bb >> 3) * 4 + ws;
        float* pbuf = (float*)smem;
        float* pf0 = pbuf + ws * 320;
        float* pf1 = pf0 + 160;

        size_t sbase = ((size_t)h * NTOK + i) * 5;
        int selr[5];
#pragma unroll
        for (int s = 0; s < 5; s++) selr[s] = selidx[sbase + s];
        int mk = selmask[h * NTOK + i];

        const _Float16* q0p = rqh + ((size_t)(h * 2 + 0) * NTOK + i) * 64 + c * 16;
        const _Float16* q1p = rqh + ((size_t)(h * 2 + 1) * NTOK + i) * 64 + c * 16;
        HU qa, qb;
        qa.v[0] = *(const uint4*)(q0p); qa.v[1] = *(const uint4*)(q0p + 8);
        qb.v[0] = *(const uint4*)(q1p); qb.v[1] = *(const uint4*)(q1p + 8);
        int iq = i & 31;

        // ---- fine QK (160 keys) ----
#pragma unroll
        for (int kt = 0; kt < 10; kt++) {
            int slot = kt >> 1;
            int blk = selr[slot];
            int key = kt * 16 + kq;
            int jj = key & 31;
            int kpos = blk * 32 + jj;
            bool valid = (slot < 4) ? (((mk >> slot) & 1) != 0) : (jj <= iq);
            const _Float16* kr = rkh + ((size_t)h * NTOK + kpos) * 64 + c * 16;
            HU kk_;
            kk_.v[0] = *(const uint4*)(kr);
            kk_.v[1] = *(const uint4*)(kr + 8);
            float s0 = 0.f, s1 = 0.f;
            dot16d(kk_, qa, qb, s0, s1);
            s0 += __shfl_xor(s0, 1); s0 += __shfl_xor(s0, 2);
            s1 += __shfl_xor(s1, 1); s1 += __shfl_xor(s1, 2);
            if (c == 0) {
                pf0[key] = valid ? s0 * SCALE : NEG10F;
                pf1[key] = valid ? s1 * SCALE : NEG10F;
            }
        }
        // ---- fine softmax over 160 (wave-local; same-wave LDS ordering) ----
        {
            float a0 = pf0[lane], b0 = pf0[lane + 64];
            float c0 = (lane < 32) ? pf0[lane + 128] : NEG10F;
            float a1 = pf1[lane], b1 = pf1[lane + 64];
            float c1 = (lane < 32) ? pf1[lane + 128] : NEG10F;
            float m0 = fmaxf(fmaxf(a0, b0), c0);
            float m1 = fmaxf(fmaxf(a1, b1), c1);
#pragma unroll
            for (int o = 1; o < 64; o <<= 1) {
                m0 = fmaxf(m0, __shfl_xor(m0, o));
                m1 = fmaxf(m1, __shfl_xor(m1, o));
            }
            float ea0 = __expf(a0 - m0), eb0 = __expf(b0 - m0), ec0 = (lane < 32) ? __expf(c0 - m0) : 0.f;
            float ea1 = __expf(a1 - m1), eb1 = __expf(b1 - m1), ec1 = (lane < 32) ? __expf(c1 - m1) : 0.f;
            float d0 = ea0 + eb0 + ec0;
            float d1 = ea1 + eb1 + ec1;
#pragma unroll
            for (int o = 1; o < 64; o <<= 1) {
                d0 += __shfl_xor(d0, o);
                d1 += __shfl_xor(d1, o);
            }
            float inv0 = 1.f / d0, inv1 = 1.f / d1;
            pf0[lane] = ea0 * inv0; pf0[lane + 64] = eb0 * inv0;
            pf1[lane] = ea1 * inv1; pf1[lane + 64] = eb1 * inv1;
            if (lane < 32) { pf0[lane + 128] = ec0 * inv0; pf1[lane + 128] = ec1 * inv1; }
        }
        // ---- fine PV (160 keys) ----
        float o0[8] = {}, o1[8] = {};
#pragma unroll
        for (int slot = 0; slot < 5; slot++) {
            const __hip_bfloat16* vbase = vt + ((size_t)h * NTOK + selr[slot] * 32) * 64;
#pragma unroll
            for (int pass = 0; pass < 4; pass++) {
                int j = pass * 8 + kv8;
                uint4 v = *(const uint4*)(vbase + j * 64 + c8 * 8);
                float pa = pf0[slot * 32 + j], pb = pf1[slot * 32 + j];
                float e0 = bflo(v.x), e1 = bfhi(v.x), e2 = bflo(v.y), e3 = bfhi(v.y);
                float e4 = bflo(v.z), e5 = bfhi(v.z), e6 = bflo(v.w), e7 = bfhi(v.w);
                o0[0] = fmaf(pa, e0, o0[0]); o0[1] = fmaf(pa, e1, o0[1]);
                o0[2] = fmaf(pa, e2, o0[2]); o0[3] = fmaf(pa, e3, o0[3]);
                o0[4] = fmaf(pa, e4, o0[4]); o0[5] = fmaf(pa, e5, o0[5]);
                o0[6] = fmaf(pa, e6, o0[6]); o0[7] = fmaf(pa, e7, o0[7]);
                o1[0] = fmaf(pb, e0, o1[0]); o1[1] = fmaf(pb, e1, o1[1]);
                o1[2] = fmaf(pb, e2, o1[2]); o1[3] = fmaf(pb, e3, o1[3]);
                o1[4] = fmaf(pb, e4, o1[4]); o1[5] = fmaf(pb, e5, o1[5]);
                o1[6] = fmaf(pb, e6, o1[6]); o1[7] = fmaf(pb, e7, o1[7]);
            }
        }
#pragma unroll
        for (int o = 8; o <= 32; o <<= 1)
#pragma unroll
            for (int d = 0; d < 8; d++) {
                o0[d] += __shfl_xor(o0[d], o);
                o1[d] += __shfl_xor(o1[d], o);
            }
        if (kv8 == 0) {
            float* f0 = fout + ((size_t)(h * 2 + 0) * NTOK + i) * 64 + c8 * 8;
            float* f1 = fout + ((size_t)(h * 2 + 1) * NTOK + i) * 64 + c8 * 8;
            *(float4*)(f0) = (float4){o0[0], o0[1], o0[2], o0[3]};
            *(float4*)(f0 + 4) = (float4){o0[4], o0[5], o0[6], o0[7]};
            *(float4*)(f1) = (float4){o1[0], o1[1], o1[2], o1[3]};
            *(float4*)(f1 + 4) = (float4){o1[4], o1[5], o1[6], o1[7]};
        }
    }
}

// ---------------- Gated combine (sigmoid applied here; writes bf16) ----------------
__global__ __launch_bounds__(256) void combine_kernel(const float* __restrict__ gateslin,
                                                      const float* __restrict__ cout,
                                                      const float* __restrict__ fout,
                                                      const float* __restrict__ sout,
                                                      __hip_bfloat16* __restrict__ att) {
    int n = blockIdx.x;
    for (int c = threadIdx.x; c < NH * HD; c += 256) {
        int hd = c >> 6, d = c & 63;
        float g0 = 1.f / (1.f + expf(-gateslin[(size_t)n * (NH * 3) + hd * 3 + 0]));
        float g1 = 1.f / (1.f + expf(-gateslin[(size_t)n * (NH * 3) + hd * 3 + 1]));
        float g2 = 1.f / (1.f + expf(-gateslin[(size_t)n * (NH * 3) + hd * 3 + 2]));
        size_t o = ((size_t)hd * NTOK + n) * HD + d;
        att[(size_t)n * (NH * HD) + c] =
            __float2bfloat16(g0 * cout[o] + g1 * fout[o] + g2 * sout[o]);
    }
}

extern "C" void kernel_launch(void* const* d_in, const int* in_sizes, int n_in,
                              void* d_out, int out_size, void* d_ws, size_t ws_size,
                              hipStream_t stream) {
    const float* inp    = (const float*)d_in[0];
    const float* norm_g = (const float*)d_in[1];
    const float* Wqkv   = (const float*)d_in[2];
    const float* mem_kv = (const float*)d_in[3];
    const float* k_pos  = (const float*)d_in[4];
    const float* v_pos  = (const float*)d_in[5];
    const float* kW1    = (const float*)d_in[6];
    const float* kb1    = (const float*)d_in[7];
    const float* kW2    = (const float*)d_in[8];
    const float* kb2    = (const float*)d_in[9];
    const float* vW1    = (const float*)d_in[10];
    const float* vb1    = (const float*)d_in[11];
    const float* vW2    = (const float*)d_in[12];
    const float* vb2    = (const float*)d_in[13];
    const float* combW  = (const float*)d_in[14];
    const float* combB  = (const float*)d_in[15];
    const float* Wout   = (const float*)d_in[16];
    float* out = (float*)d_out;

    char* base = (char*)d_ws;
    size_t off = 0;
    auto alloc = [&](size_t bytes) {
        void* p = base + off;
        off += (bytes + 255) & ~(size_t)255;
        return p;
    };
    __hip_bfloat16* xb  = (__hip_bfloat16*)alloc((size_t)NTOK * DIM * 2);
    float* qkv          = (float*)alloc((size_t)NTOK * 2048 * 4);
    __hip_bfloat16* Wqkvt = (__hip_bfloat16*)alloc((size_t)2048 * 1024 * 2);
    __hip_bfloat16* kW1t  = (__hip_bfloat16*)alloc((size_t)2048 * 2048 * 2);
    __hip_bfloat16* vW1t  = (__hip_bfloat16*)alloc((size_t)2048 * 2048 * 2);
    __hip_bfloat16* Woutt = (__hip_bfloat16*)alloc((size_t)1024 * 1024 * 2);
    __hip_bfloat16* combWt = (__hip_bfloat16*)alloc((size_t)48 * 1024 * 2);
    __hip_bfloat16* kW2t  = (__hip_bfloat16*)alloc((size_t)64 * 2048 * 2);
    __hip_bfloat16* vW2t  = (__hip_bfloat16*)alloc((size_t)64 * 2048 * 2);
    __hip_bfloat16* kwflat = (__hip_bfloat16*)alloc((size_t)KVH * NCB * HIDN * 2);
    __hip_bfloat16* vwflat = (__hip_bfloat16*)alloc((size_t)KVH * NCB * HIDN * 2);
    __hip_bfloat16* hidkb = (__hip_bfloat16*)alloc((size_t)KVH * NCB * HIDN * 2);
    __hip_bfloat16* hidvb = (__hip_bfloat16*)alloc((size_t)KVH * NCB * HIDN * 2);
    float* ckraw        = (float*)alloc((size_t)KVH * NCB * HD * 4);
    float* cvraw        = (float*)alloc((size_t)KVH * NCB * HD * 4);
    _Float16* rqh       = (_Float16*)alloc((size_t)NH * NTOK * HD * 2);
    _Float16* rkh       = (_Float16*)alloc((size_t)KVH * NTOK * HD * 2);
    __hip_bfloat16* vt  = (__hip_bfloat16*)alloc((size_t)KVH * NTOK * HD * 2);
    float* coutb        = (float*)alloc((size_t)NH * NTOK * HD * 4);
    float* foutb        = (float*)alloc((size_t)NH * NTOK * HD * 4);
    float* soutb        = (float*)alloc((size_t)NH * NTOK * HD * 4);
    float* gatesb       = (float*)alloc((size_t)NTOK * NH * 3 * 4);
    __hip_bfloat16* attb = (__hip_bfloat16*)alloc((size_t)NTOK * DIM * 2);
    int* selidx         = (int*)alloc((size_t)KVH * NTOK * 5 * 4);
    int* selmask        = (int*)alloc((size_t)KVH * NTOK * 4);
    (void)ws_size; (void)in_sizes; (void)n_in; (void)out_size;

    // 1. rmsnorm + weight transposes + bias inits
    pre_kernel<<<PRE_BLOCKS, 256, 0, stream>>>(inp, norm_g, xb,
                                               Wqkv, Wqkvt, kW1, kW1t, vW1, vW1t,
                                               Wout, Woutt, combW, combWt,
                                               kW2, kW2t, vW2, vW2t,
                                               combB, gatesb, kb2, ckraw, vb2, cvraw);
    // 2. qkv GEMM (128x64 tiles, 512 blocks) + gates split-K
    qkv_gates_kernel<<<576, 256, 0, stream>>>(xb, Wqkvt, qkv, combWt, gatesb);
    // 3. build compressed windows + RoPE (Q/K written f16)
    winrope_kernel<<<4096 + 2048, 256, 0, stream>>>(qkv, k_pos, v_pos, kwflat, vwflat,
                                                    rqh, rkh, vt);
    // 4. compressed k/v MLP layer 1 (128x64 tiles, 512 blocks)
    gemm64_pair<<<dim3(32, 8, 2), 256, 0, stream>>>(kwflat, vwflat, kW1t, vW1t,
                                                    kb1, vb1, hidkb, hidvb,
                                                    1024, 2048, 2048);
    // 5. compressed k/v MLP layer 2 (batched split-K)
    skgemm_pair<<<dim3(2, 8, 8), 256, 0, stream>>>(hidkb, hidvb, kW2t, vW2t,
                                                   ckraw, cvraw, 1024, 64, 2048);
    // 6. compressed attention + importance + fused top-k (no ck/cv staging)
    cattn3_kernel<<<KVH * (NTOK / 32), 256, 0, stream>>>(qkv, ckraw, cvraw, mem_kv,
                                                         coutb, selidx, selmask);
    // 7. fused tiled-sliding + fine attention, fdot2 QK, XCD h-swizzle
    attn_fused7_kernel<<<SLIDE_BLKS + 4096, 256, 0, stream>>>(rqh, rkh, vt, selidx, selmask,
                                                              foutb, soutb);
    // 8. gated combine
    combine_kernel<<<NTOK, 256, 0, stream>>>(gatesb, coutb, foutb, soutb, attb);
    // 9. out projection (128x64 tiles, 256 blocks)
    gemm64<0, 0><<<dim3(16, 16), 256, 0, stream>>>(attb, Woutt, nullptr, out, 2048, 1024, 1024);
}

// Round 10
// 351.846 us; speedup vs baseline: 1.1866x; 1.1866x over previous
//
#include <hip/hip_runtime.h>
#include <hip/hip_bf16.h>

// Problem constants
#define NTOK 2048
#define DIM 1024
#define NH 16
#define KVH 8
#define GQ 2
#define HD 64
#define WS 64
#define CBS 32
#define STRIDE 16
#define SEL_BLK 32
#define NSEL 4
#define NMEM 1
#define NCB 128          // N/STRIDE
#define NFB 64           // N/SEL_BLK
#define HIDN 2048        // CBS*D
#define SCALE 0.125f
#define NEGF (-3.4028234663852886e38f)
#define NEG10F (-3.4028234663852886e37f)

typedef __attribute__((ext_vector_type(8))) short bf16x8;
typedef __attribute__((ext_vector_type(4))) float f32x4;
typedef _Float16 f16x2 __attribute__((ext_vector_type(2)));

__device__ __forceinline__ float bflo(unsigned u) { return __uint_as_float(u << 16); }
__device__ __forceinline__ float bfhi(unsigned u) { return __uint_as_float(u & 0xffff0000u); }

// f16 packed fragment: 16 halfs = 2 uint4 = 8 half2
union HU { uint4 v[2]; f16x2 h[8]; };

// dot of 16 f16 elems (k) against two queries via v_dot2_f32_f16:
// 4 independent f32 accumulator chains (depth 4) -> keeps ILP (round-5 lesson:
// packed-f16 FMA with 2 chains of 8 was latency-bound).
__device__ __forceinline__ void dot16d(const HU& k, const HU& qa, const HU& qb,
                                       float& s0, float& s1) {
    float a0 = 0.f, a1 = 0.f, b0 = 0.f, b1 = 0.f;
#pragma unroll
    for (int j = 0; j < 8; j += 2) {
        a0 = __builtin_amdgcn_fdot2(k.h[j], qa.h[j], a0, false);
        a1 = __builtin_amdgcn_fdot2(k.h[j + 1], qa.h[j + 1], a1, false);
        b0 = __builtin_amdgcn_fdot2(k.h[j], qb.h[j], b0, false);
        b1 = __builtin_amdgcn_fdot2(k.h[j + 1], qb.h[j + 1], b1, false);
    }
    s0 += a0 + a1;
    s1 += b0 + b1;
}

// async 16B global -> LDS (LDS dest must be wave-uniform base + lane*16)
__device__ __forceinline__ void gload_lds16(const void* g, void* l) {
    __builtin_amdgcn_global_load_lds((const __attribute__((address_space(1))) unsigned*)g,
                                     (__attribute__((address_space(3))) unsigned*)l, 16, 0, 0);
}

// ---------------- RMSNorm body (f32 x output removed: dead) ----------------
__device__ __forceinline__ void rms_body(const float* __restrict__ inp,
                                         const float* __restrict__ g,
                                         __hip_bfloat16* __restrict__ xb, int n) {
    const float* row = inp + (size_t)n * DIM;
    float ss = 0.f;
    for (int c = threadIdx.x; c < DIM; c += 256) { float v = row[c]; ss += v * v; }
    __shared__ float red[4];
    for (int o = 32; o; o >>= 1) ss += __shfl_down(ss, o, 64);
    if ((threadIdx.x & 63) == 0) red[threadIdx.x >> 6] = ss;
    __syncthreads();
    if (threadIdx.x == 0) red[0] = red[0] + red[1] + red[2] + red[3];
    __syncthreads();
    float rs = 1.0f / sqrtf(red[0] / (float)DIM + 1.1920928955078125e-07f);
    __hip_bfloat16* xbr = xb + (size_t)n * DIM;
    for (int c = threadIdx.x; c < DIM; c += 256) {
        float v = row[c] * rs * g[c];
        xbr[c] = __float2bfloat16(v);
    }
}

// ---------------- transpose body ----------------
__device__ __forceinline__ void transpose_body(const float* __restrict__ B,
                                               __hip_bfloat16* __restrict__ Bt,
                                               int K, int N, int bx, int by) {
    __shared__ float tile[32][33];
    int n0 = bx * 32, k0 = by * 32;
    int x = threadIdx.x & 31, y = threadIdx.x >> 5;
    for (int i = 0; i < 4; i++) {
        int k = k0 + y + 8 * i, n = n0 + x;
        tile[y + 8 * i][x] = (k < K && n < N) ? B[(size_t)k * N + n] : 0.f;
    }
    __syncthreads();
    for (int i = 0; i < 4; i++) {
        int n = n0 + y + 8 * i, k = k0 + x;
        if (n < N && k < K) Bt[(size_t)n * K + k] = __float2bfloat16(tile[x][y + 8 * i]);
    }
}

// ---------------- pre: rmsnorm + all transposes + bias inits ----------------
__global__ __launch_bounds__(256) void pre_kernel(
    const float* inp, const float* norm_g, __hip_bfloat16* xb,
    const float* Wqkv, __hip_bfloat16* Wqkvt,
    const float* kW1, __hip_bfloat16* kW1t,
    const float* vW1, __hip_bfloat16* vW1t,
    const float* Wout, __hip_bfloat16* Woutt,
    const float* combW, __hip_bfloat16* combWt,
    const float* kW2, __hip_bfloat16* kW2t,
    const float* vW2, __hip_bfloat16* vW2t,
    const float* combB, float* gatesb,
    const float* kb2, float* ckraw,
    const float* vb2, float* cvraw) {
    int b = blockIdx.x;
    if (b < 2048) { rms_body(inp, norm_g, xb, b); return; }
    b -= 2048;
    if (b < 2048) { transpose_body(Wqkv, Wqkvt, 1024, 2048, b % 64, b / 64); return; }
    b -= 2048;
    if (b < 4096) { transpose_body(kW1, kW1t, 2048, 2048, b % 64, b / 64); return; }
    b -= 4096;
    if (b < 4096) { transpose_body(vW1, vW1t, 2048, 2048, b % 64, b / 64); return; }
    b -= 4096;
    if (b < 1024) { transpose_body(Wout, Woutt, 1024, 1024, b % 32, b / 32); return; }
    b -= 1024;
    if (b < 64) { transpose_body(combW, combWt, 1024, 48, b % 2, b / 2); return; }
    b -= 64;
    if (b < 128) { transpose_body(kW2, kW2t, 2048, 64, b % 2, b / 2); return; }
    b -= 128;
    if (b < 128) { transpose_body(vW2, vW2t, 2048, 64, b % 2, b / 2); return; }
    b -= 128;
    if (b < 384) {  // gates bias init: 2048*48
        int idx = b * 256 + threadIdx.x;
        if (idx < 2048 * 48) gatesb[idx] = combB[idx % 48];
        return;
    }
    b -= 384;
    {   // ck/cv bias init: 2*1024*64
        int idx = b * 256 + threadIdx.x;
        int tot = 1024 * 64;
        if (idx < tot) ckraw[idx] = kb2[idx % 64];
        else if (idx < 2 * tot) { idx -= tot; cvraw[idx] = vb2[idx % 64]; }
        return;
    }
}
#define PRE_BLOCKS (2048 + 2048 + 4096 + 4096 + 1024 + 64 + 128 + 128 + 384 + 512)

// ---------------- 128x64-tile bf16 MFMA GEMM body (2+ blocks/CU occupancy) --------
template <int ACT, int OUTBF16>
__device__ __forceinline__ void gemm64_body(const __hip_bfloat16* __restrict__ A,
                                            const __hip_bfloat16* __restrict__ Bt,
                                            const float* __restrict__ bias,
                                            void* __restrict__ Cp,
                                            int M, int N, int K, int bx, int by) {
    __shared__ __align__(16) short As2[128 * 32];
    __shared__ __align__(16) short Bs2[64 * 32];
    int tid = threadIdx.x;
    int lane = tid & 63, wave = tid >> 6;
    int m0 = by * 128, n0 = bx * 64;
    int wm = wave * 32;
    f32x4 acc[2][4];
    for (int r = 0; r < 2; r++)
        for (int c = 0; c < 4; c++) acc[r][c] = (f32x4){0.f, 0.f, 0.f, 0.f};

    int ra = tid >> 2, kc = (tid & 3) * 8;
    for (int k0 = 0; k0 < K; k0 += 32) {
        __syncthreads();
        gload_lds16(A + (size_t)(m0 + ra) * K + k0 + kc, &As2[ra * 32 + kc]);
        gload_lds16(A + (size_t)(m0 + ra + 64) * K + k0 + kc, &As2[(ra + 64) * 32 + kc]);
        gload_lds16(Bt + (size_t)(n0 + ra) * K + k0 + kc, &Bs2[ra * 32 + kc]);
        __syncthreads();
        bf16x8 af[2], bfr[4];
#pragma unroll
        for (int r = 0; r < 2; r++)
            af[r] = *(const bf16x8*)&As2[(wm + r * 16 + (lane & 15)) * 32 + (lane >> 4) * 8];
#pragma unroll
        for (int c = 0; c < 4; c++)
            bfr[c] = *(const bf16x8*)&Bs2[(c * 16 + (lane & 15)) * 32 + (lane >> 4) * 8];
#pragma unroll
        for (int r = 0; r < 2; r++)
#pragma unroll
            for (int c = 0; c < 4; c++)
                acc[r][c] = __builtin_amdgcn_mfma_f32_16x16x32_bf16(af[r], bfr[c], acc[r][c], 0, 0, 0);
    }
    for (int r = 0; r < 2; r++) {
        int grow = m0 + wm + r * 16 + (lane >> 4) * 4;
        for (int c = 0; c < 4; c++) {
            int gcol = n0 + c * 16 + (lane & 15);
            float bv = bias ? bias[gcol] : 0.f;
#pragma unroll
            for (int v = 0; v < 4; v++) {
                float val = acc[r][c][v] + bv;
                if (ACT == 1) val = fmaxf(val, 0.f);
                if (OUTBF16)
                    ((__hip_bfloat16*)Cp)[(size_t)(grow + v) * N + gcol] = __float2bfloat16(val);
                else
                    ((float*)Cp)[(size_t)(grow + v) * N + gcol] = val;
            }
        }
    }
}

template <int ACT, int OUTBF16>
__global__ __launch_bounds__(256) void gemm64(const __hip_bfloat16* __restrict__ A,
                                              const __hip_bfloat16* __restrict__ Bt,
                                              const float* __restrict__ bias,
                                              void* __restrict__ Cp,
                                              int M, int N, int K) {
    gemm64_body<ACT, OUTBF16>(A, Bt, bias, Cp, M, N, K, blockIdx.x, blockIdx.y);
}

__global__ __launch_bounds__(256) void gemm64_pair(const __hip_bfloat16* A0,
                                                   const __hip_bfloat16* A1,
                                                   const __hip_bfloat16* Bt0,
                                                   const __hip_bfloat16* Bt1,
                                                   const float* bias0, const float* bias1,
                                                   __hip_bfloat16* C0, __hip_bfloat16* C1,
                                                   int M, int N, int K) {
    if (blockIdx.z == 0)
        gemm64_body<1, 1>(A0, Bt0, bias0, C0, M, N, K, blockIdx.x, blockIdx.y);
    else
        gemm64_body<1, 1>(A1, Bt1, bias1, C1, M, N, K, blockIdx.x, blockIdx.y);
}

// ---------------- Split-K skinny MFMA GEMM body: C += A @ Bt^T (atomicAdd) ----------
__device__ __forceinline__ void skgemm_body(const __hip_bfloat16* __restrict__ A,
                                            const __hip_bfloat16* __restrict__ Bt,
                                            float* __restrict__ C,
                                            int M, int Nout, int K, int by, int bz, int nz) {
    __shared__ __align__(16) short As2[128 * 32];
    __shared__ __align__(16) short Bs2[64 * 32];
    int tid = threadIdx.x;
    int lane = tid & 63, wave = tid >> 6;
    int m0 = by * 128;
    int wm = wave * 32;
    int kchunk = K / nz;
    int kbase = bz * kchunk;
    f32x4 acc[2][4];
    for (int r = 0; r < 2; r++)
        for (int c = 0; c < 4; c++) acc[r][c] = (f32x4){0.f, 0.f, 0.f, 0.f};

    int ra = tid >> 2, kc = (tid & 3) * 8;
    int rb = ra < Nout ? ra : Nout - 1;
    for (int k0 = kbase; k0 < kbase + kchunk; k0 += 32) {
        __syncthreads();
        gload_lds16(A + (size_t)(m0 + ra) * K + k0 + kc, &As2[ra * 32 + kc]);
        gload_lds16(A + (size_t)(m0 + ra + 64) * K + k0 + kc, &As2[(ra + 64) * 32 + kc]);
        gload_lds16(Bt + (size_t)rb * K + k0 + kc, &Bs2[ra * 32 + kc]);
        __syncthreads();
        bf16x8 af[2], bfr[4];
#pragma unroll
        for (int r = 0; r < 2; r++)
            af[r] = *(const bf16x8*)&As2[(wm + r * 16 + (lane & 15)) * 32 + (lane >> 4) * 8];
#pragma unroll
        for (int c = 0; c < 4; c++)
            bfr[c] = *(const bf16x8*)&Bs2[(c * 16 + (lane & 15)) * 32 + (lane >> 4) * 8];
#pragma unroll
        for (int r = 0; r < 2; r++)
#pragma unroll
            for (int c = 0; c < 4; c++)
                acc[r][c] = __builtin_amdgcn_mfma_f32_16x16x32_bf16(af[r], bfr[c], acc[r][c], 0, 0, 0);
    }
    for (int r = 0; r < 2; r++) {
        int grow = m0 + wm + r * 16 + (lane >> 4) * 4;
        for (int c = 0; c < 4; c++) {
            int gcol = c * 16 + (lane & 15);
            if (gcol >= Nout) continue;
#pragma unroll
            for (int v = 0; v < 4; v++)
                atomicAdd(&C[(size_t)(grow + v) * Nout + gcol], acc[r][c][v]);
        }
    }
}

// ---------------- qkv GEMM + gates split-K in one launch ----------------
__global__ __launch_bounds__(256) void qkv_gates_kernel(const __hip_bfloat16* xb,
                                                        const __hip_bfloat16* Wqkvt,
                                                        float* qkv,
                                                        const __hip_bfloat16* combWt,
                                                        float* gatesb) {
    int b = blockIdx.x;
    if (b < 512) {
        gemm64_body<0, 0>(xb, Wqkvt, nullptr, qkv, 2048, 2048, 1024, b & 31, b >> 5);
    } else {
        int s = b - 512;  // 64 blocks: by = s&15, bz = s>>4 (nz=4)
        skgemm_body(xb, combWt, gatesb, 2048, 48, 1024, s & 15, s >> 4, 4);
    }
}

__global__ __launch_bounds__(256) void skgemm_pair(const __hip_bfloat16* A0,
                                                   const __hip_bfloat16* A1,
                                                   const __hip_bfloat16* Bt0,
                                                   const __hip_bfloat16* Bt1,
                                                   float* C0, float* C1,
                                                   int M, int Nout, int K) {
    if (blockIdx.x == 0)
        skgemm_body(A0, Bt0, C0, M, Nout, K, blockIdx.y, blockIdx.z, gridDim.z);
    else
        skgemm_body(A1, Bt1, C1, M, Nout, K, blockIdx.y, blockIdx.z, gridDim.z);
}

// ---------------- buildwin + rope fused (Q and K written as f16) ----------------
__global__ __launch_bounds__(256) void winrope_kernel(const float* __restrict__ qkv,
                                                      const float* __restrict__ k_pos,
                                                      const float* __restrict__ v_pos,
                                                      __hip_bfloat16* __restrict__ kwflat,
                                                      __hip_bfloat16* __restrict__ vwflat,
                                                      _Float16* __restrict__ rqh,
                                                      _Float16* __restrict__ rkh,
                                                      __hip_bfloat16* __restrict__ vt) {
    int b = blockIdx.x;
    int t = threadIdx.x;
    if (b < 4096) {
        size_t total = (size_t)(KVH * NCB) * HIDN;
        for (size_t e = (size_t)b * 256 + t; e < total; e += (size_t)4096 * 256) {
            int r = (int)(e >> 11);
            int c = (int)(e & 2047);
            int j = c >> 6, d = c & 63;
            int h = r >> 7, i = r & 127;
            int p = i * STRIDE + j - (CBS - STRIDE);
            float kb = k_pos[((size_t)h * CBS + j) * HD + d];
            float vb = v_pos[((size_t)h * CBS + j) * HD + d];
            float kv = 0.f, vv = 0.f;
            if (p >= 0) {
                kv = qkv[(size_t)p * 2048 + 1024 + h * HD + d];
                vv = qkv[(size_t)p * 2048 + 1536 + h * HD + d];
            }
            kwflat[e] = __float2bfloat16(kv + kb);
            vwflat[e] = __float2bfloat16(vv + vb);
        }
        return;
    }
    int n = b - 4096;
    for (int idx = t; idx < NH * 32; idx += 256) {
        int h = idx >> 5, f = idx & 31;
        float inv = exp2f((float)f * -0.41524101186092f);
        float ang = (float)n * inv;
        float cc = cosf(ang), ssn = sinf(ang);
        float a = qkv[(size_t)n * 2048 + h * HD + 2 * f];
        float bq = qkv[(size_t)n * 2048 + h * HD + 2 * f + 1];
        _Float16* o = rqh + ((size_t)h * NTOK + n) * HD + 2 * f;
        o[0] = (_Float16)(a * cc - bq * ssn);
        o[1] = (_Float16)(bq * cc + a * ssn);
    }
    for (int idx = t; idx < KVH * 32; idx += 256) {
        int h = idx >> 5, f = idx & 31;
        float inv = exp2f((float)f * -0.41524101186092f);
        float ang = (float)n * inv;
        float cc = cosf(ang), ssn = sinf(ang);
        float a = qkv[(size_t)n * 2048 + 1024 + h * HD + 2 * f];
        float bq = qkv[(size_t)n * 2048 + 1024 + h * HD + 2 * f + 1];
        _Float16* o = rkh + ((size_t)h * NTOK + n) * HD + 2 * f;
        o[0] = (_Float16)(a * cc - bq * ssn);
        o[1] = (_Float16)(bq * cc + a * ssn);
    }
    for (int idx = t; idx < KVH * HD; idx += 256) {
        int h = idx >> 6, d = idx & 63;
        vt[((size_t)h * NTOK + n) * HD + d] =
            __float2bfloat16(qkv[(size_t)n * 2048 + 1536 + h * HD + d]);
    }
}

// ---------------- Compressed attention + importance + fused top-k ----------------
// (round-8 cattn2 restored: LDS staging for ck/cv is essential — the round-9
// direct-global variant was latency-bound at 13% VALUBusy, 117 us)
__global__ __launch_bounds__(256) void cattn2_kernel(const float* __restrict__ qkv,
                                                     const float* __restrict__ ckraw,
                                                     const float* __restrict__ cvraw,
                                                     const float* __restrict__ memkv,
                                                     float* __restrict__ cout,
                                                     int* __restrict__ selidx,
                                                     int* __restrict__ selmask) {
    int h = blockIdx.x >> 6;
    int i0 = (blockIdx.x & 63) * 32;
    int t = threadIdx.x;
    __shared__ float qs[64][68];
    __shared__ float sc[64][132];
    __shared__ float scratch[32 * 68];
    __shared__ float memk[64], memv[64];

    for (int idx = t; idx < 4096; idx += 256) {
        int row = idx >> 6, d = idx & 63;
        int g = row >> 5, qi = row & 31;
        qs[row][d] = qkv[(size_t)(i0 + qi) * 2048 + (h * 2 + g) * 64 + d];
    }
    if (t < 64) { memk[t] = memkv[h * 64 + t]; memv[t] = memkv[(8 + h) * 64 + t]; }
    __syncthreads();
    if (t < 64) {
        float s = 0.f;
        for (int d = 0; d < 64; d++) s += qs[t][d] * memk[d];
        sc[t][0] = s * SCALE;
    }
    int rg = t >> 3, kg = t & 7;
    for (int c = 0; c < 4; c++) {
        __syncthreads();
        for (int idx = t; idx < 2048; idx += 256) {
            int jj = idx >> 6, d = idx & 63;
            scratch[jj * 68 + d] = ckraw[((size_t)h * 128 + c * 32 + jj) * 64 + d];
        }
        __syncthreads();
        float a0[4] = {}, a1[4] = {};
        for (int d = 0; d < 64; d += 4) {
            float4 q0 = *(const float4*)&qs[rg * 2][d];
            float4 q1 = *(const float4*)&qs[rg * 2 + 1][d];
#pragma unroll
            for (int kk = 0; kk < 4; kk++) {
                float4 kv = *(const float4*)&scratch[(kg + kk * 8) * 68 + d];
                a0[kk] += q0.x * kv.x + q0.y * kv.y + q0.z * kv.z + q0.w * kv.w;
                a1[kk] += q1.x * kv.x + q1.y * kv.y + q1.z * kv.z + q1.w * kv.w;
            }
        }
#pragma unroll
        for (int kk = 0; kk < 4; kk++) {
            sc[rg * 2][1 + c * 32 + kg + kk * 8] = a0[kk] * SCALE;
            sc[rg * 2 + 1][1 + c * 32 + kg + kk * 8] = a1[kk] * SCALE;
        }
    }
    __syncthreads();
    for (int idx = t; idx < 2048; idx += 256) {
        int qi = idx >> 6, fb = idx & 63;
        float v = 0.25f * (sc[qi][1 + 2 * fb] + sc[qi][2 + 2 * fb] +
                           sc[32 + qi][1 + 2 * fb] + sc[32 + qi][2 + 2 * fb]);
        if (fb == ((i0 + qi) >> 5)) v = NEGF;
        scratch[qi * 66 + fb] = v;
    }
    __syncthreads();
    if (t < 32) {
        float* row = &scratch[t * 66];
        float m = -1000.f;
        for (int j = 0; j < 64; j++) m = fmaxf(m, row[j]);
        float den = __expf(-1000.f - m);
        for (int j = 0; j < 64; j++) den += __expf(row[j] - m);
        float invd = 1.f / den;
        unsigned long long taken = 0ull;
        int mk = 0;
        size_t base = ((size_t)h * NTOK + i0 + t) * 5;
        for (int p = 0; p < NSEL; p++) {
            float bv = NEGF;
            int bi = 0;
            for (int j = 0; j < 64; j++) {
                if (!((taken >> j) & 1ull) && row[j] > bv) { bv = row[j]; bi = j; }
            }
            taken |= 1ull << bi;
            selidx[base + p] = bi;
            if (__expf(bv - m) * invd > 1e-10f) mk |= 1 << p;
        }
        selidx[base + 4] = (i0 + t) >> 5;
        selmask[h * NTOK + i0 + t] = mk;
    } else if (t >= 64 && t < 128) {
        int r = t - 64;
        float m = NEGF;
        for (int j = 0; j < 129; j++) m = fmaxf(m, sc[r][j]);
        float den = 0.f;
        for (int j = 0; j < 129; j++) { float e = __expf(sc[r][j] - m); sc[r][j] = e; den += e; }
        float inv = 1.f / den;
        for (int j = 0; j < 129; j++) sc[r][j] *= inv;
    }
    __syncthreads();
    int dg = t & 7;
    float o0[8], o1[8];
    {
        float p0 = sc[rg * 2][0], p1 = sc[rg * 2 + 1][0];
#pragma unroll
        for (int dd = 0; dd < 8; dd++) {
            float v = memv[dg + dd * 8];
            o0[dd] = p0 * v;
            o1[dd] = p1 * v;
        }
    }
    for (int c = 0; c < 4; c++) {
        __syncthreads();
        for (int idx = t; idx < 2048; idx += 256) {
            int jj = idx >> 6, d = idx & 63;
            scratch[jj * 68 + d] = cvraw[((size_t)h * 128 + c * 32 + jj) * 64 + d];
        }
        __syncthreads();
        for (int jj = 0; jj < 32; jj++) {
            float p0 = sc[rg * 2][1 + c * 32 + jj];
            float p1 = sc[rg * 2 + 1][1 + c * 32 + jj];
#pragma unroll
            for (int dd = 0; dd < 8; dd++) {
                float v = scratch[jj * 68 + dg + dd * 8];
                o0[dd] += p0 * v;
                o1[dd] += p1 * v;
            }
        }
    }
    {
        int row = rg * 2;
        int g = row >> 5, qi = row & 31;
        int g2 = (row + 1) >> 5, qi2 = (row + 1) & 31;
#pragma unroll
        for (int dd = 0; dd < 8; dd++) {
            cout[(((size_t)(h * 2 + g)) * NTOK + i0 + qi) * 64 + dd * 8 + dg] = o0[dd];
            cout[(((size_t)(h * 2 + g2)) * NTOK + i0 + qi2) * 64 + dd * 8 + dg] = o1[dd];
        }
    }
}

// ---------------- Fused attention v7: fdot2 QK ------------------------------------
// Structure = v6 (K-only LDS sliding, V direct, h = blk&7 XCD swizzle). QK uses
// v_dot2_f32_f16 (__builtin_amdgcn_fdot2): 2 f16 MACs/inst, f32 accumulation,
// 4 independent accumulator chains of depth 4 (preserves ILP; round-5's hfma2
// failure was 2 chains of 8 in f16). PV unchanged (bf16 V, f32 FMA).
#define SLIDE_BLKS 1024
#define SROWS 79          // 16 queries + 63 history rows
#define SPAD 72           // shorts per K row (144 B, 16B-aligned, bank-rotated)
#define SLIDE_LDS (SROWS * SPAD * 2 + 4 * 128 * 4)   // 13424 B
__global__ __launch_bounds__(256) void attn_fused7_kernel(const _Float16* __restrict__ rqh,
                                                          const _Float16* __restrict__ rkh,
                                                          const __hip_bfloat16* __restrict__ vt,
                                                          const int* __restrict__ selidx,
                                                          const int* __restrict__ selmask,
                                                          float* __restrict__ fout,
                                                          float* __restrict__ sout) {
    int tid = threadIdx.x;
    int ws = tid >> 6, lane = tid & 63;
    __shared__ __align__(16) char smem[SLIDE_LDS];

    int kq = lane >> 2, c = lane & 3;
    int kv8 = lane >> 3, c8 = lane & 7;

    if (blockIdx.x < SLIDE_BLKS) {
        // ---------- tiled sliding-window: h = blk&7, 16-query tile ----------
        int h = blockIdx.x & 7;
        int q0 = (int)(blockIdx.x >> 3) * 16;
        short* ks = (short*)smem;
        float* ps = (float*)(smem + SROWS * SPAD * 2);
        int basek = q0 - 63;
        for (int idx = tid; idx < SROWS * 8; idx += 256) {
            int row = idx >> 3, ch = (idx & 7) * 8;
            int kpos = basek + row;
            uint4 kv = (uint4){0u, 0u, 0u, 0u};
            if (kpos >= 0)
                kv = *(const uint4*)(rkh + ((size_t)h * NTOK + kpos) * 64 + ch);
            *(uint4*)&ks[row * SPAD + ch] = kv;
        }
        __syncthreads();
        float* p0 = ps + ws * 128;
        float* p1 = p0 + 64;
#pragma unroll 1
        for (int tq = 0; tq < 4; tq++) {
            int ibase = ws * 4 + tq;
            int i = q0 + ibase;
            const _Float16* q0p = rqh + ((size_t)(h * 2 + 0) * NTOK + i) * 64 + c * 16;
            const _Float16* q1p = rqh + ((size_t)(h * 2 + 1) * NTOK + i) * 64 + c * 16;
            HU qa, qb;
            qa.v[0] = *(const uint4*)(q0p); qa.v[1] = *(const uint4*)(q0p + 8);
            qb.v[0] = *(const uint4*)(q1p); qb.v[1] = *(const uint4*)(q1p + 8);
#pragma unroll
            for (int kt = 0; kt < 4; kt++) {
                int key = kt * 16 + kq;
                const short* kr = &ks[(ibase + key) * SPAD + c * 16];
                HU kk_;
                kk_.v[0] = *(const uint4*)(kr);
                kk_.v[1] = *(const uint4*)(kr + 8);
                float s0 = 0.f, s1 = 0.f;
                dot16d(kk_, qa, qb, s0, s1);
                s0 += __shfl_xor(s0, 1); s0 += __shfl_xor(s0, 2);
                s1 += __shfl_xor(s1, 1); s1 += __shfl_xor(s1, 2);
                int kpos = i - 63 + key;
                if (c == 0) {
                    p0[key] = (kpos >= 0) ? s0 * SCALE : NEG10F;
                    p1[key] = (kpos >= 0) ? s1 * SCALE : NEG10F;
                }
            }
            // wave-local softmax over 64 (same-wave LDS ordering is program-order)
            {
                float a0 = p0[lane], a1 = p1[lane];
                float m0 = a0, m1 = a1;
#pragma unroll
                for (int o = 1; o < 64; o <<= 1) {
                    m0 = fmaxf(m0, __shfl_xor(m0, o));
                    m1 = fmaxf(m1, __shfl_xor(m1, o));
                }
                float e0 = __expf(a0 - m0), e1 = __expf(a1 - m1);
                float d0 = e0, d1 = e1;
#pragma unroll
                for (int o = 1; o < 64; o <<= 1) {
                    d0 += __shfl_xor(d0, o);
                    d1 += __shfl_xor(d1, o);
                }
                p0[lane] = e0 / d0;
                p1[lane] = e1 / d1;
            }
            // sliding PV: V direct from global (L2-resident; masked keys have p==0,
            // so clamped row index is safe)
            float o0[8] = {}, o1[8] = {};
#pragma unroll
            for (int pass = 0; pass < 8; pass++) {
                int j = pass * 8 + kv8;
                int kpos = i - 63 + j;
                int kcl = kpos >= 0 ? kpos : 0;
                uint4 v = *(const uint4*)(vt + ((size_t)h * NTOK + kcl) * 64 + c8 * 8);
                float pa = p0[j], pb = p1[j];
                float e0 = bflo(v.x), e1 = bfhi(v.x), e2 = bflo(v.y), e3 = bfhi(v.y);
                float e4 = bflo(v.z), e5 = bfhi(v.z), e6 = bflo(v.w), e7 = bfhi(v.w);
                o0[0] = fmaf(pa, e0, o0[0]); o0[1] = fmaf(pa, e1, o0[1]);
                o0[2] = fmaf(pa, e2, o0[2]); o0[3] = fmaf(pa, e3, o0[3]);
                o0[4] = fmaf(pa, e4, o0[4]); o0[5] = fmaf(pa, e5, o0[5]);
                o0[6] = fmaf(pa, e6, o0[6]); o0[7] = fmaf(pa, e7, o0[7]);
                o1[0] = fmaf(pb, e0, o1[0]); o1[1] = fmaf(pb, e1, o1[1]);
                o1[2] = fmaf(pb, e2, o1[2]); o1[3] = fmaf(pb, e3, o1[3]);
                o1[4] = fmaf(pb, e4, o1[4]); o1[5] = fmaf(pb, e5, o1[5]);
                o1[6] = fmaf(pb, e6, o1[6]); o1[7] = fmaf(pb, e7, o1[7]);
            }
#pragma unroll
            for (int o = 8; o <= 32; o <<= 1)
#pragma unroll
                for (int d = 0; d < 8; d++) {
                    o0[d] += __shfl_xor(o0[d], o);
                    o1[d] += __shfl_xor(o1[d], o);
                }
            if (kv8 == 0) {
                float* s0p = sout + ((size_t)(h * 2 + 0) * NTOK + i) * 64 + c8 * 8;
                float* s1p = sout + ((size_t)(h * 2 + 1) * NTOK + i) * 64 + c8 * 8;
                *(float4*)(s0p) = (float4){o0[0], o0[1], o0[2], o0[3]};
                *(float4*)(s0p + 4) = (float4){o0[4], o0[5], o0[6], o0[7]};
                *(float4*)(s1p) = (float4){o1[0], o1[1], o1[2], o1[3]};
                *(float4*)(s1p + 4) = (float4){o1[4], o1[5], o1[6], o1[7]};
            }
        }
    } else {
        // ---------- fine attention (wave per query), h = blk&7 ----------
        int bb = blockIdx.x - SLIDE_BLKS;
        int h = bb & 7;
        int i = (bb >> 3) * 4 + ws;
        float* pbuf = (float*)smem;
        float* pf0 = pbuf + ws * 320;
        float* pf1 = pf0 + 160;

        size_t sbase = ((size_t)h * NTOK + i) * 5;
        int selr[5];
#pragma unroll
        for (int s = 0; s < 5; s++) selr[s] = selidx[sbase + s];
        int mk = selmask[h * NTOK + i];

        const _Float16* q0p = rqh + ((size_t)(h * 2 + 0) * NTOK + i) * 64 + c * 16;
        const _Float16* q1p = rqh + ((size_t)(h * 2 + 1) * NTOK + i) * 64 + c * 16;
        HU qa, qb;
        qa.v[0] = *(const uint4*)(q0p); qa.v[1] = *(const uint4*)(q0p + 8);
        qb.v[0] = *(const uint4*)(q1p); qb.v[1] = *(const uint4*)(q1p + 8);
        int iq = i & 31;

        // ---- fine QK (160 keys) ----
#pragma unroll
        for (int kt = 0; kt < 10; kt++) {
            int slot = kt >> 1;
            int blk = selr[slot];
            int key = kt * 16 + kq;
            int jj = key & 31;
            int kpos = blk * 32 + jj;
            bool valid = (slot < 4) ? (((mk >> slot) & 1) != 0) : (jj <= iq);
            const _Float16* kr = rkh + ((size_t)h * NTOK + kpos) * 64 + c * 16;
            HU kk_;
            kk_.v[0] = *(const uint4*)(kr);
            kk_.v[1] = *(const uint4*)(kr + 8);
            float s0 = 0.f, s1 = 0.f;
            dot16d(kk_, qa, qb, s0, s1);
            s0 += __shfl_xor(s0, 1); s0 += __shfl_xor(s0, 2);
            s1 += __shfl_xor(s1, 1); s1 += __shfl_xor(s1, 2);
            if (c == 0) {
                pf0[key] = valid ? s0 * SCALE : NEG10F;
                pf1[key] = valid ? s1 * SCALE : NEG10F;
            }
        }
        // ---- fine softmax over 160 (wave-local; same-wave LDS ordering) ----
        {
            float a0 = pf0[lane], b0 = pf0[lane + 64];
            float c0 = (lane < 32) ? pf0[lane + 128] : NEG10F;
            float a1 = pf1[lane], b1 = pf1[lane + 64];
            float c1 = (lane < 32) ? pf1[lane + 128] : NEG10F;
            float m0 = fmaxf(fmaxf(a0, b0), c0);
            float m1 = fmaxf(fmaxf(a1, b1), c1);
#pragma unroll
            for (int o = 1; o < 64; o <<= 1) {
                m0 = fmaxf(m0, __shfl_xor(m0, o));
                m1 = fmaxf(m1, __shfl_xor(m1, o));
            }
            float ea0 = __expf(a0 - m0), eb0 = __expf(b0 - m0), ec0 = (lane < 32) ? __expf(c0 - m0) : 0.f;
            float ea1 = __expf(a1 - m1), eb1 = __expf(b1 - m1), ec1 = (lane < 32) ? __expf(c1 - m1) : 0.f;
            float d0 = ea0 + eb0 + ec0;
            float d1 = ea1 + eb1 + ec1;
#pragma unroll
            for (int o = 1; o < 64; o <<= 1) {
                d0 += __shfl_xor(d0, o);
                d1 += __shfl_xor(d1, o);
            }
            float inv0 = 1.f / d0, inv1 = 1.f / d1;
            pf0[lane] = ea0 * inv0; pf0[lane + 64] = eb0 * inv0;
            pf1[lane] = ea1 * inv1; pf1[lane + 64] = eb1 * inv1;
            if (lane < 32) { pf0[lane + 128] = ec0 * inv0; pf1[lane + 128] = ec1 * inv1; }
        }
        // ---- fine PV (160 keys) ----
        float o0[8] = {}, o1[8] = {};
#pragma unroll
        for (int slot = 0; slot < 5; slot++) {
            const __hip_bfloat16* vbase = vt + ((size_t)h * NTOK + selr[slot] * 32) * 64;
#pragma unroll
            for (int pass = 0; pass < 4; pass++) {
                int j = pass * 8 + kv8;
                uint4 v = *(const uint4*)(vbase + j * 64 + c8 * 8);
                float pa = pf0[slot * 32 + j], pb = pf1[slot * 32 + j];
                float e0 = bflo(v.x), e1 = bfhi(v.x), e2 = bflo(v.y), e3 = bfhi(v.y);
                float e4 = bflo(v.z), e5 = bfhi(v.z), e6 = bflo(v.w), e7 = bfhi(v.w);
                o0[0] = fmaf(pa, e0, o0[0]); o0[1] = fmaf(pa, e1, o0[1]);
                o0[2] = fmaf(pa, e2, o0[2]); o0[3] = fmaf(pa, e3, o0[3]);
                o0[4] = fmaf(pa, e4, o0[4]); o0[5] = fmaf(pa, e5, o0[5]);
                o0[6] = fmaf(pa, e6, o0[6]); o0[7] = fmaf(pa, e7, o0[7]);
                o1[0] = fmaf(pb, e0, o1[0]); o1[1] = fmaf(pb, e1, o1[1]);
                o1[2] = fmaf(pb, e2, o1[2]); o1[3] = fmaf(pb, e3, o1[3]);
                o1[4] = fmaf(pb, e4, o1[4]); o1[5] = fmaf(pb, e5, o1[5]);
                o1[6] = fmaf(pb, e6, o1[6]); o1[7] = fmaf(pb, e7, o1[7]);
            }
        }
#pragma unroll
        for (int o = 8; o <= 32; o <<= 1)
#pragma unroll
            for (int d = 0; d < 8; d++) {
                o0[d] += __shfl_xor(o0[d], o);
                o1[d] += __shfl_xor(o1[d], o);
            }
        if (kv8 == 0) {
            float* f0 = fout + ((size_t)(h * 2 + 0) * NTOK + i) * 64 + c8 * 8;
            float* f1 = fout + ((size_t)(h * 2 + 1) * NTOK + i) * 64 + c8 * 8;
            *(float4*)(f0) = (float4){o0[0], o0[1], o0[2], o0[3]};
            *(float4*)(f0 + 4) = (float4){o0[4], o0[5], o0[6], o0[7]};
            *(float4*)(f1) = (float4){o1[0], o1[1], o1[2], o1[3]};
            *(float4*)(f1 + 4) = (float4){o1[4], o1[5], o1[6], o1[7]};
        }
    }
}

// ---------------- Gated combine (sigmoid applied here; writes bf16) ----------------
__global__ __launch_bounds__(256) void combine_kernel(const float* __restrict__ gateslin,
                                                      const float* __restrict__ cout,
                                                      const float* __restrict__ fout,
                                                      const float* __restrict__ sout,
                                                      __hip_bfloat16* __restrict__ att) {
    int n = blockIdx.x;
    for (int c = threadIdx.x; c < NH * HD; c += 256) {
        int hd = c >> 6, d = c & 63;
        float g0 = 1.f / (1.f + expf(-gateslin[(size_t)n * (NH * 3) + hd * 3 + 0]));
        float g1 = 1.f / (1.f + expf(-gateslin[(size_t)n * (NH * 3) + hd * 3 + 1]));
        float g2 = 1.f / (1.f + expf(-gateslin[(size_t)n * (NH * 3) + hd * 3 + 2]));
        size_t o = ((size_t)hd * NTOK + n) * HD + d;
        att[(size_t)n * (NH * HD) + c] =
            __float2bfloat16(g0 * cout[o] + g1 * fout[o] + g2 * sout[o]);
    }
}

extern "C" void kernel_launch(void* const* d_in, const int* in_sizes, int n_in,
                              void* d_out, int out_size, void* d_ws, size_t ws_size,
                              hipStream_t stream) {
    const float* inp    = (const float*)d_in[0];
    const float* norm_g = (const float*)d_in[1];
    const float* Wqkv   = (const float*)d_in[2];
    const float* mem_kv = (const float*)d_in[3];
    const float* k_pos  = (const float*)d_in[4];
    const float* v_pos  = (const float*)d_in[5];
    const float* kW1    = (const float*)d_in[6];
    const float* kb1    = (const float*)d_in[7];
    const float* kW2    = (const float*)d_in[8];
    const float* kb2    = (const float*)d_in[9];
    const float* vW1    = (const float*)d_in[10];
    const float* vb1    = (const float*)d_in[11];
    const float* vW2    = (const float*)d_in[12];
    const float* vb2    = (const float*)d_in[13];
    const float* combW  = (const float*)d_in[14];
    const float* combB  = (const float*)d_in[15];
    const float* Wout   = (const float*)d_in[16];
    float* out = (float*)d_out;

    char* base = (char*)d_ws;
    size_t off = 0;
    auto alloc = [&](size_t bytes) {
        void* p = base + off;
        off += (bytes + 255) & ~(size_t)255;
        return p;
    };
    __hip_bfloat16* xb  = (__hip_bfloat16*)alloc((size_t)NTOK * DIM * 2);
    float* qkv          = (float*)alloc((size_t)NTOK * 2048 * 4);
    __hip_bfloat16* Wqkvt = (__hip_bfloat16*)alloc((size_t)2048 * 1024 * 2);
    __hip_bfloat16* kW1t  = (__hip_bfloat16*)alloc((size_t)2048 * 2048 * 2);
    __hip_bfloat16* vW1t  = (__hip_bfloat16*)alloc((size_t)2048 * 2048 * 2);
    __hip_bfloat16* Woutt = (__hip_bfloat16*)alloc((size_t)1024 * 1024 * 2);
    __hip_bfloat16* combWt = (__hip_bfloat16*)alloc((size_t)48 * 1024 * 2);
    __hip_bfloat16* kW2t  = (__hip_bfloat16*)alloc((size_t)64 * 2048 * 2);
    __hip_bfloat16* vW2t  = (__hip_bfloat16*)alloc((size_t)64 * 2048 * 2);
    __hip_bfloat16* kwflat = (__hip_bfloat16*)alloc((size_t)KVH * NCB * HIDN * 2);
    __hip_bfloat16* vwflat = (__hip_bfloat16*)alloc((size_t)KVH * NCB * HIDN * 2);
    __hip_bfloat16* hidkb = (__hip_bfloat16*)alloc((size_t)KVH * NCB * HIDN * 2);
    __hip_bfloat16* hidvb = (__hip_bfloat16*)alloc((size_t)KVH * NCB * HIDN * 2);
    float* ckraw        = (float*)alloc((size_t)KVH * NCB * HD * 4);
    float* cvraw        = (float*)alloc((size_t)KVH * NCB * HD * 4);
    _Float16* rqh       = (_Float16*)alloc((size_t)NH * NTOK * HD * 2);
    _Float16* rkh       = (_Float16*)alloc((size_t)KVH * NTOK * HD * 2);
    __hip_bfloat16* vt  = (__hip_bfloat16*)alloc((size_t)KVH * NTOK * HD * 2);
    float* coutb        = (float*)alloc((size_t)NH * NTOK * HD * 4);
    float* foutb        = (float*)alloc((size_t)NH * NTOK * HD * 4);
    float* soutb        = (float*)alloc((size_t)NH * NTOK * HD * 4);
    float* gatesb       = (float*)alloc((size_t)NTOK * NH * 3 * 4);
    __hip_bfloat16* attb = (__hip_bfloat16*)alloc((size_t)NTOK * DIM * 2);
    int* selidx         = (int*)alloc((size_t)KVH * NTOK * 5 * 4);
    int* selmask        = (int*)alloc((size_t)KVH * NTOK * 4);
    (void)ws_size; (void)in_sizes; (void)n_in; (void)out_size;

    // 1. rmsnorm + weight transposes + bias inits
    pre_kernel<<<PRE_BLOCKS, 256, 0, stream>>>(inp, norm_g, xb,
                                               Wqkv, Wqkvt, kW1, kW1t, vW1, vW1t,
                                               Wout, Woutt, combW, combWt,
                                               kW2, kW2t, vW2, vW2t,
                                               combB, gatesb, kb2, ckraw, vb2, cvraw);
    // 2. qkv GEMM (128x64 tiles, 512 blocks) + gates split-K
    qkv_gates_kernel<<<576, 256, 0, stream>>>(xb, Wqkvt, qkv, combWt, gatesb);
    // 3. build compressed windows + RoPE (Q/K written f16)
    winrope_kernel<<<4096 + 2048, 256, 0, stream>>>(qkv, k_pos, v_pos, kwflat, vwflat,
                                                    rqh, rkh, vt);
    // 4. compressed k/v MLP layer 1 (128x64 tiles, 512 blocks)
    gemm64_pair<<<dim3(32, 8, 2), 256, 0, stream>>>(kwflat, vwflat, kW1t, vW1t,
                                                    kb1, vb1, hidkb, hidvb,
                                                    1024, 2048, 2048);
    // 5. compressed k/v MLP layer 2 (batched split-K)
    skgemm_pair<<<dim3(2, 8, 8), 256, 0, stream>>>(hidkb, hidvb, kW2t, vW2t,
                                                   ckraw, cvraw, 1024, 64, 2048);
    // 6. compressed attention + importance + fused top-k (LDS-staged, round-8 form)
    cattn2_kernel<<<KVH * (NTOK / 32), 256, 0, stream>>>(qkv, ckraw, cvraw, mem_kv,
                                                         coutb, selidx, selmask);
    // 7. fused tiled-sliding + fine attention, fdot2 QK, XCD h-swizzle
    attn_fused7_kernel<<<SLIDE_BLKS + 4096, 256, 0, stream>>>(rqh, rkh, vt, selidx, selmask,
                                                              foutb, soutb);
    // 8. gated combine
    combine_kernel<<<NTOK, 256, 0, stream>>>(gatesb, coutb, foutb, soutb, attb);
    // 9. out projection (128x64 tiles, 256 blocks)
    gemm64<0, 0><<<dim3(16, 16), 256, 0, stream>>>(attb, Woutt, nullptr, out, 2048, 1024, 1024);
}